// Round 2
// baseline (45080.246 us; speedup 1.0000x reference)
//
#include <hip/hip_runtime.h>
#include <hip/hip_bf16.h>
#include <math.h>

typedef __hip_bfloat16 bf16;

#define B_   4
#define S_   1024
#define D_   512
#define H_   8
#define DK_  64
#define DFF_ 2048
#define L_   6
#define V_   16000
#define NT_  (B_ * S_)   // 4096 tokens

// Runtime dtype flag: 1 if float tensors are bf16 on device, 0 if f32.
// Detected from enc_ln_g (all ones): bf16 -> first two u16 both 0x3F80.
__global__ void detect_kernel(const void* __restrict__ g, int* __restrict__ flag)
{
    const unsigned short* u = (const unsigned short*)g;
    *flag = (u[0] == 0x3F80 && u[1] == 0x3F80) ? 1 : 0;
}

__device__ __forceinline__ float ldw(const void* p, size_t i, int isbf)
{
    if (isbf) return __bfloat162float(((const bf16*)p)[i]);
    return ((const float*)p)[i];
}

// ---------------------------------------------------------------------------
// Embedding + positional encoding: X[bs,d] = emb[tok[bs]][d] + pe(s,d)
// ---------------------------------------------------------------------------
__global__ __launch_bounds__(256)
void embed_kernel(const int* __restrict__ tok, const void* __restrict__ emb,
                  float* __restrict__ X, const int* __restrict__ flagp)
{
    const int isbf = *flagp;
    int idx = blockIdx.x * 256 + threadIdx.x;      // < NT_*D_ (exact multiple)
    int d  = idx & (D_ - 1);
    int bs = idx >> 9;                              // D_=512 -> shift 9
    int s  = bs & (S_ - 1);
    int t  = tok[bs];
    float e = ldw(emb, (size_t)t * D_ + d, isbf);
    float expo = (float)(d & ~1) * (1.0f / (float)D_);
    float div  = powf(10000.0f, expo);
    float arg  = (float)s / div;
    float pe   = (d & 1) ? cosf(arg) : sinf(arg);
    X[idx] = e + pe;
}

// ---------------------------------------------------------------------------
// GEMM: C[M,N] = A[M,K](f32) * W[K,N](flag dtype) + bias [+res(f32)] [relu]
// Output: Cout (d_out, dtype per flag) if non-null, else Cf (f32 ws).
// 64x64 block tile, 256 threads, 4x4 micro-tile. All dims multiples of 64/16.
// ---------------------------------------------------------------------------
__global__ __launch_bounds__(256)
void gemm_f32_kernel(const float* __restrict__ A,
                     const void* __restrict__ W, size_t w_off,
                     const void* __restrict__ bias, size_t b_off,
                     const float* __restrict__ res,
                     float* __restrict__ Cf, void* __restrict__ Cout,
                     int M, int N, int K, int relu,
                     const int* __restrict__ flagp)
{
    __shared__ __align__(16) float As[16][68];   // [k][m]
    __shared__ __align__(16) float Bs[16][68];   // [k][n]

    const int isbf = *flagp;
    const int tid = threadIdx.x;
    const int tx = tid & 15;       // n-dir
    const int ty = tid >> 4;       // m-dir
    const int row0 = blockIdx.y * 64;
    const int col0 = blockIdx.x * 64;

    float acc[4][4] = {{0.f}};

    for (int k0 = 0; k0 < K; k0 += 16) {
#pragma unroll
        for (int i = 0; i < 4; ++i) {            // A tile: 64x16
            int idx = tid + i * 256;
            int m = idx >> 4, kk = idx & 15;
            As[kk][m] = A[(size_t)(row0 + m) * K + k0 + kk];
        }
#pragma unroll
        for (int i = 0; i < 4; ++i) {            // W tile: 16x64
            int idx = tid + i * 256;
            int kk = idx >> 6, n = idx & 63;
            Bs[kk][n] = ldw(W, w_off + (size_t)(k0 + kk) * N + col0 + n, isbf);
        }
        __syncthreads();
#pragma unroll
        for (int kk = 0; kk < 16; ++kk) {
            float4 a4 = *(const float4*)&As[kk][ty * 4];
            float4 b4 = *(const float4*)&Bs[kk][tx * 4];
            float av[4] = {a4.x, a4.y, a4.z, a4.w};
            float bv[4] = {b4.x, b4.y, b4.z, b4.w};
#pragma unroll
            for (int i = 0; i < 4; ++i)
#pragma unroll
                for (int j = 0; j < 4; ++j)
                    acc[i][j] += av[i] * bv[j];
        }
        __syncthreads();
    }

#pragma unroll
    for (int i = 0; i < 4; ++i) {
        int m = row0 + ty * 4 + i;
#pragma unroll
        for (int j = 0; j < 4; ++j) {
            int n = col0 + tx * 4 + j;
            float v = acc[i][j] + ldw(bias, b_off + n, isbf);
            if (res)  v += res[(size_t)m * N + n];
            if (relu) v = fmaxf(v, 0.f);
            size_t oidx = (size_t)m * N + n;
            if (Cout) {
                if (isbf) ((bf16*)Cout)[oidx] = __float2bfloat16(v);
                else      ((float*)Cout)[oidx] = v;
            } else {
                Cf[oidx] = v;
            }
        }
    }
}

// ---------------------------------------------------------------------------
// Attention: one block per (q-position, head, batch). Q/K/V layout [B,S,H,DK]
// (== [B,S,D] row-major). causal => keys 0..q only. All f32 (workspace).
// ---------------------------------------------------------------------------
__global__ __launch_bounds__(256)
void attn_kernel(const float* __restrict__ Q, const float* __restrict__ Kp,
                 const float* __restrict__ Vp, float* __restrict__ O,
                 int Skv, int causal)
{
    const int qpos = blockIdx.x, h = blockIdx.y, b = blockIdx.z;
    const int tid  = threadIdx.x;
    const int Lkv  = causal ? (qpos + 1) : Skv;

    __shared__ float qs[DK_];
    __shared__ float sc[S_];
    __shared__ float red[256];

    const float* qrow = Q + ((size_t)(b * S_ + qpos) * H_ + h) * DK_;
    if (tid < DK_) qs[tid] = qrow[tid];
    __syncthreads();

    const float scale = 0.125f;   // 1/sqrt(64)
    float lmax = -INFINITY;
    for (int j = tid; j < Lkv; j += 256) {
        const float* krow = Kp + ((size_t)(b * S_ + j) * H_ + h) * DK_;
        float d = 0.f;
#pragma unroll
        for (int t = 0; t < DK_; ++t) d += qs[t] * krow[t];
        d *= scale;
        sc[j] = d;
        lmax = fmaxf(lmax, d);
    }
    red[tid] = lmax;
    __syncthreads();
    for (int s = 128; s > 0; s >>= 1) {
        if (tid < s) red[tid] = fmaxf(red[tid], red[tid + s]);
        __syncthreads();
    }
    float mx = red[0];
    __syncthreads();

    float lsum = 0.f;
    for (int j = tid; j < Lkv; j += 256) {
        float p = expf(sc[j] - mx);
        sc[j] = p;
        lsum += p;
    }
    red[tid] = lsum;
    __syncthreads();
    for (int s = 128; s > 0; s >>= 1) {
        if (tid < s) red[tid] += red[tid + s];
        __syncthreads();
    }
    float inv = 1.0f / red[0];
    __syncthreads();

    // PV: thread t -> d = t&63, partial over j = (t>>6)::4
    int d = tid & 63, part = tid >> 6;
    float acc = 0.f;
    for (int j = part; j < Lkv; j += 4)
        acc += sc[j] * Vp[((size_t)(b * S_ + j) * H_ + h) * DK_ + d];
    red[tid] = acc;
    __syncthreads();
    if (tid < DK_) {
        float o = (red[tid] + red[64 + tid] + red[128 + tid] + red[192 + tid]) * inv;
        O[((size_t)(b * S_ + qpos) * H_ + h) * DK_ + tid] = o;
    }
}

// ---------------------------------------------------------------------------
// LayerNorm over rows of 512. One block per row. eps = 1e-5.
// ---------------------------------------------------------------------------
__global__ __launch_bounds__(256)
void layernorm_kernel(const float* __restrict__ X,
                      const void* __restrict__ g, size_t g_off,
                      const void* __restrict__ bb, size_t b_off,
                      float* __restrict__ Y, const int* __restrict__ flagp)
{
    __shared__ float red[256];
    const int isbf = *flagp;
    const int row = blockIdx.x, tid = threadIdx.x;
    const float* x = X + (size_t)row * D_;
    float v0 = x[tid], v1 = x[tid + 256];
    red[tid] = v0 + v1;
    __syncthreads();
    for (int s = 128; s > 0; s >>= 1) {
        if (tid < s) red[tid] += red[tid + s];
        __syncthreads();
    }
    float mean = red[0] * (1.0f / (float)D_);
    __syncthreads();
    float d0 = v0 - mean, d1 = v1 - mean;
    red[tid] = d0 * d0 + d1 * d1;
    __syncthreads();
    for (int s = 128; s > 0; s >>= 1) {
        if (tid < s) red[tid] += red[tid + s];
        __syncthreads();
    }
    float r = rsqrtf(red[0] * (1.0f / (float)D_) + 1e-5f);
    float* y = Y + (size_t)row * D_;
    y[tid]       = ldw(g, g_off + tid, isbf)       * d0 * r + ldw(bb, b_off + tid, isbf);
    y[tid + 256] = ldw(g, g_off + tid + 256, isbf) * d1 * r + ldw(bb, b_off + tid + 256, isbf);
}

// ---------------------------------------------------------------------------
extern "C" void kernel_launch(void* const* d_in, const int* in_sizes, int n_in,
                              void* d_out, int out_size, void* d_ws, size_t ws_size,
                              hipStream_t stream)
{
    (void)in_sizes; (void)n_in; (void)out_size;

    const int*  src      = (const int*)d_in[0];
    const int*  tgt      = (const int*)d_in[1];
    // d_in[2] = tgt_mask: deterministic causal triu -> recomputed, never read
    const void* src_emb  = d_in[3];
    const void* tgt_emb  = d_in[4];
    const void* eaw      = d_in[5];   // [L,4,D,D]
    const void* eab      = d_in[6];   // [L,4,D]
    const void* ew1      = d_in[7];   // [L,D,DFF]
    const void* eb1      = d_in[8];   // [L,DFF]
    const void* ew2      = d_in[9];   // [L,DFF,D]
    const void* eb2      = d_in[10];  // [L,D]
    const void* elg      = d_in[11];  // [L,2,D]
    const void* elb      = d_in[12];  // [L,2,D]
    const void* daw      = d_in[13];  // [L,8,D,D]
    const void* dab      = d_in[14];  // [L,8,D]
    const void* dw1      = d_in[15];
    const void* db1      = d_in[16];
    const void* dw2      = d_in[17];
    const void* db2      = d_in[18];
    const void* dlg      = d_in[19];  // [L,3,D]
    const void* dlb      = d_in[20];  // [L,3,D]
    const void* gen_w    = d_in[21];  // [D,V]
    const void* gen_b    = d_in[22];  // [V]

    // workspace carve-up
    const size_t tokD = (size_t)NT_ * D_;          // 2,097,152
    const size_t tokF = (size_t)NT_ * DFF_;        // 8,388,608
    const size_t need = 256 + (6 * tokD + tokF) * sizeof(float);
    if (ws_size < need) return;                    // visible failure, no OOB

    int*   flagp = (int*)d_ws;
    float* xbuf = (float*)((char*)d_ws + 256);     // encoder state
    float* ybuf = xbuf + tokD;         // decoder state
    float* qbuf = ybuf + tokD;         // q proj / pre-LN tmp
    float* kbuf = qbuf + tokD;
    float* vbuf = kbuf + tokD;
    float* abuf = vbuf + tokD;         // attention output
    float* fbuf = abuf + tokD;         // ffn mid [NT, DFF]
    float* tbuf = qbuf;                // pre-LN tmp (q dead by then)

    detect_kernel<<<1, 1, 0, stream>>>(elg, flagp);

    auto gemm = [&](const float* A, const void* W, size_t w_off,
                    const void* bias, size_t b_off, const float* res,
                    float* Cf, void* Cout, int M, int N, int K, int relu) {
        dim3 g(N / 64, M / 64);
        gemm_f32_kernel<<<g, 256, 0, stream>>>(A, W, w_off, bias, b_off, res,
                                               Cf, Cout, M, N, K, relu, flagp);
    };
    auto attn = [&](const float* Q, const float* Kp, const float* Vp,
                    float* O, int causal) {
        dim3 g(S_, H_, B_);
        attn_kernel<<<g, 256, 0, stream>>>(Q, Kp, Vp, O, S_, causal);
    };
    auto ln = [&](const float* X, const void* g_, size_t g_off,
                  const void* b_, size_t b_off, float* Y) {
        layernorm_kernel<<<NT_, 256, 0, stream>>>(X, g_, g_off, b_, b_off, Y, flagp);
    };

    // ---- embeddings ----
    embed_kernel<<<(NT_ * D_) / 256, 256, 0, stream>>>(src, src_emb, xbuf, flagp);
    embed_kernel<<<(NT_ * D_) / 256, 256, 0, stream>>>(tgt, tgt_emb, ybuf, flagp);

    const size_t DD = (size_t)D_ * D_;

    // ---- encoder ----
    for (int i = 0; i < L_; ++i) {
        size_t w0 = (size_t)i * 4 * DD;
        size_t b0 = (size_t)i * 4 * D_;
        gemm(xbuf, eaw, w0 + 0 * DD, eab, b0 + 0 * D_, nullptr, qbuf, nullptr, NT_, D_, D_, 0);
        gemm(xbuf, eaw, w0 + 1 * DD, eab, b0 + 1 * D_, nullptr, kbuf, nullptr, NT_, D_, D_, 0);
        gemm(xbuf, eaw, w0 + 2 * DD, eab, b0 + 2 * D_, nullptr, vbuf, nullptr, NT_, D_, D_, 0);
        attn(qbuf, kbuf, vbuf, abuf, 0);
        gemm(abuf, eaw, w0 + 3 * DD, eab, b0 + 3 * D_, xbuf, tbuf, nullptr, NT_, D_, D_, 0);
        ln(tbuf, elg, (size_t)(i * 2 + 0) * D_, elb, (size_t)(i * 2 + 0) * D_, xbuf);
        gemm(xbuf, ew1, (size_t)i * D_ * DFF_, eb1, (size_t)i * DFF_,
             nullptr, fbuf, nullptr, NT_, DFF_, D_, 1);
        gemm(fbuf, ew2, (size_t)i * DFF_ * D_, eb2, (size_t)i * D_,
             xbuf, tbuf, nullptr, NT_, D_, DFF_, 0);
        ln(tbuf, elg, (size_t)(i * 2 + 1) * D_, elb, (size_t)(i * 2 + 1) * D_, xbuf);
    }

    // ---- decoder ----
    for (int i = 0; i < L_; ++i) {
        size_t w0 = (size_t)i * 8 * DD;
        size_t b0 = (size_t)i * 8 * D_;
        // masked self-attention
        gemm(ybuf, daw, w0 + 0 * DD, dab, b0 + 0 * D_, nullptr, qbuf, nullptr, NT_, D_, D_, 0);
        gemm(ybuf, daw, w0 + 1 * DD, dab, b0 + 1 * D_, nullptr, kbuf, nullptr, NT_, D_, D_, 0);
        gemm(ybuf, daw, w0 + 2 * DD, dab, b0 + 2 * D_, nullptr, vbuf, nullptr, NT_, D_, D_, 0);
        attn(qbuf, kbuf, vbuf, abuf, 1);
        gemm(abuf, daw, w0 + 3 * DD, dab, b0 + 3 * D_, ybuf, tbuf, nullptr, NT_, D_, D_, 0);
        ln(tbuf, dlg, (size_t)(i * 3 + 0) * D_, dlb, (size_t)(i * 3 + 0) * D_, ybuf);
        // cross-attention (kv from encoder output)
        gemm(ybuf, daw, w0 + 4 * DD, dab, b0 + 4 * D_, nullptr, qbuf, nullptr, NT_, D_, D_, 0);
        gemm(xbuf, daw, w0 + 5 * DD, dab, b0 + 5 * D_, nullptr, kbuf, nullptr, NT_, D_, D_, 0);
        gemm(xbuf, daw, w0 + 6 * DD, dab, b0 + 6 * D_, nullptr, vbuf, nullptr, NT_, D_, D_, 0);
        attn(qbuf, kbuf, vbuf, abuf, 0);
        gemm(abuf, daw, w0 + 7 * DD, dab, b0 + 7 * D_, ybuf, tbuf, nullptr, NT_, D_, D_, 0);
        ln(tbuf, dlg, (size_t)(i * 3 + 1) * D_, dlb, (size_t)(i * 3 + 1) * D_, ybuf);
        // FFN
        gemm(ybuf, dw1, (size_t)i * D_ * DFF_, db1, (size_t)i * DFF_,
             nullptr, fbuf, nullptr, NT_, DFF_, D_, 1);
        gemm(fbuf, dw2, (size_t)i * DFF_ * D_, db2, (size_t)i * D_,
             ybuf, tbuf, nullptr, NT_, D_, DFF_, 0);
        ln(tbuf, dlg, (size_t)(i * 3 + 2) * D_, dlb, (size_t)(i * 3 + 2) * D_, ybuf);
    }

    // ---- generator -> d_out (dtype per flag) ----
    gemm(ybuf, gen_w, 0, gen_b, 0, nullptr, nullptr, d_out, NT_, V_, D_, 0);
}